// Round 11
// baseline (178.135 us; speedup 1.0000x reference)
//
#include <hip/hip_runtime.h>
#include <hip/hip_bf16.h>

#define N_NODES 50000
#define N_EDGES 800000
#define DIM_IN  128
#define DIM_OUT 64
#define HEADS   4
#define NEG_SLOPE 0.2f
#define NPB 64                                    // nodes per gemm block (was 32)
#define GEMM_BLOCKS ((N_NODES + NPB - 1) / NPB)   // 782
#define N_PAD (GEMM_BLOCKS * NPB)                 // 50048
#define PAD 64                                    // sdst row: [0]=deg, [1..63]=dsts
#define MAXD 63                                   // max stored dsts per node
#define CHUNKS 128                                // edge chunks
#define EPC (N_EDGES / CHUNKS)                    // 6250 edges per chunk
#define RANGES 128                                // src ranges (single-writer CSR build)
#define RSPAN 391                                 // 128*391 = 50048 >= N_NODES
#define BCAP 128                                  // bucket capacity (mean 49, +10 sigma safe)
#define XROW 136                                  // LDS row stride (shorts) for x hi/lo
#define LTROW 260                                 // LDS row stride (shorts) for transpose buffer
#define SMEM_BYTES (2 * NPB * XROW * 2)           // 34816

typedef __attribute__((ext_vector_type(8))) short short8;
typedef __attribute__((ext_vector_type(4))) short short4v;
typedef __attribute__((ext_vector_type(4))) float f32x4;

// bf16 helpers (RNE pack, exact shift unpack)
__device__ __forceinline__ unsigned int f2bf(float f) {
    unsigned int u = __float_as_uint(f);
    return (u + 0x7FFFu + ((u >> 16) & 1u)) >> 16;
}
__device__ __forceinline__ float bf2f(unsigned int b) {
    return __uint_as_float(b << 16);
}

// ---- pack W into MFMA B-frag hi/lo; i = fragment-lane 0..4095
__device__ __forceinline__ void packW_role(
    int i, const float* __restrict__ W,
    unsigned short* __restrict__ Wph, unsigned short* __restrict__ Wpl)
{
    const int lane = i & 63, nt = (i >> 6) & 3, kc = (i >> 8) & 3, h = (i >> 10) & 3;
    const int col = lane & 15, quad = lane >> 4;
    unsigned short hv[8], lv[8];
#pragma unroll
    for (int j = 0; j < 8; ++j) {
        const int k = kc * 32 + quad * 8 + j;
        const int n = nt * 16 + col;
        const float f = W[h * (DIM_IN * DIM_OUT) + k * DIM_OUT + n];
        const unsigned int hb = f2bf(f);
        hv[j] = (unsigned short)hb;
        lv[j] = (unsigned short)f2bf(f - bf2f(hb));
    }
    *(short8*)(Wph + (size_t)i * 8) = *(short8*)hv;
    *(short8*)(Wpl + (size_t)i * 8) = *(short8*)lv;
}

// ---------------- D1: pack W (blocks 0-7) + SINGLE-PASS bucket scatter (8..135) ---
__global__ __launch_bounds__(512) void bucket_kernel(
    const float* __restrict__ W, unsigned short* __restrict__ Wph,
    unsigned short* __restrict__ Wpl, const int* __restrict__ ei,
    unsigned int* __restrict__ ebuf2, unsigned short* __restrict__ cnt)
{
    const int b = blockIdx.x;
    const int t = threadIdx.x;
    if (b < 8) { packW_role(b * 512 + t, W, Wph, Wpl); return; }

    __shared__ unsigned int cur[RANGES];
    const int c = b - 8;
    if (t < RANGES) cur[t] = 0u;
    __syncthreads();
    const int* srcp = ei + c * EPC;
    const int* dstp = ei + N_EDGES + c * EPC;
    unsigned int* bb = ebuf2 + (size_t)c * RANGES * BCAP;
    for (int e = t; e < EPC; e += 512) {
        const int s = srcp[e];
        const int d = dstp[e];
        const int r = s / RSPAN;
        const unsigned int pos = atomicAdd(&cur[r], 1u);
        if (pos < BCAP)
            bb[(size_t)r * BCAP + pos] = ((unsigned int)(s - r * RSPAN) << 16) | (unsigned int)d;
    }
    __syncthreads();
    if (t < RANGES) cnt[c * RANGES + t] = (unsigned short)min(cur[t], (unsigned int)BCAP);
}

// ---- MFMA gemm tile for nodes [nb, nb+64) (256 threads, smem = 34816 B)
// NPB=64: 12 MFMAs per B-fragment load (was 6), half the barriers per node,
// acc[4][4] pushes VGPR ~110-130 so the compiler can pipeline B-frag loads deeper.
__device__ __forceinline__ void gemm_role(
    int nb, int t, const float* __restrict__ x,
    const unsigned short* __restrict__ Wph, const unsigned short* __restrict__ Wpl,
    const float* __restrict__ a, unsigned short* __restrict__ h2,
    float* __restrict__ s_i, float* __restrict__ s_j, void* smemv)
{
    short* xh = (short*)smemv;            // [NPB][XROW]
    short* xl = xh + NPB * XROW;

    // stage x tile as hi/lo bf16 (hi = truncation, lo = RNE residual: hi+lo ~ fp32)
    {
        const float4* xg = (const float4*)x;
        const int base = nb * (DIM_IN / 4);
        const int limit = N_NODES * (DIM_IN / 4);
#pragma unroll
        for (int r = 0; r < 8; ++r) {
            const int idx = t + 256 * r;              // 0..2047
            const int gi = base + idx;
            float4 v = {0.f, 0.f, 0.f, 0.f};
            if (gi < limit) v = xg[gi];
            const int node = idx >> 5;
            const int dg = (idx & 31) * 4;
            unsigned short hs[4], ls[4];
            const float fv[4] = {v.x, v.y, v.z, v.w};
#pragma unroll
            for (int c = 0; c < 4; ++c) {
                const unsigned int hb = __float_as_uint(fv[c]) >> 16;  // trunc hi (1 op)
                hs[c] = (unsigned short)hb;
                ls[c] = (unsigned short)f2bf(fv[c] - bf2f(hb));        // exact residual
            }
            *(short4v*)(xh + node * XROW + dg) = *(short4v*)hs;
            *(short4v*)(xl + node * XROW + dg) = *(short4v*)ls;
        }
    }
    __syncthreads();

    const int w = t >> 6;        // wave id == head
    const int lane = t & 63;
    const int col = lane & 15, quad = lane >> 4;

    f32x4 acc[4][4];
#pragma unroll
    for (int mt = 0; mt < 4; ++mt)
#pragma unroll
        for (int nt = 0; nt < 4; ++nt) acc[mt][nt] = (f32x4){0.f, 0.f, 0.f, 0.f};

    const short8* Bh = (const short8*)Wph;
    const short8* Bl = (const short8*)Wpl;
#pragma unroll
    for (int kc = 0; kc < 4; ++kc) {
        short8 ah[4], al[4];
#pragma unroll
        for (int mt = 0; mt < 4; ++mt) {
            ah[mt] = *(const short8*)(xh + (mt * 16 + col) * XROW + kc * 32 + quad * 8);
            al[mt] = *(const short8*)(xl + (mt * 16 + col) * XROW + kc * 32 + quad * 8);
        }
#pragma unroll
        for (int nt = 0; nt < 4; ++nt) {
            const int fi = ((w * 4 + kc) * 4 + nt) * 64 + lane;
            const short8 bh = Bh[fi];
            const short8 bl = Bl[fi];
#pragma unroll
            for (int mt = 0; mt < 4; ++mt) {
                acc[mt][nt] = __builtin_amdgcn_mfma_f32_16x16x32_bf16(ah[mt], bh, acc[mt][nt], 0, 0, 0);
                acc[mt][nt] = __builtin_amdgcn_mfma_f32_16x16x32_bf16(al[mt], bh, acc[mt][nt], 0, 0, 0);
                acc[mt][nt] = __builtin_amdgcn_mfma_f32_16x16x32_bf16(ah[mt], bl, acc[mt][nt], 0, 0, 0);
            }
        }
    }

    // scores: lane holds h[node=mt*16+quad*4+r][head=w][o=nt*16+col]
    float aiv[4], ajv[4];
#pragma unroll
    for (int nt = 0; nt < 4; ++nt) {
        aiv[nt] = a[w * (2 * DIM_OUT) + nt * 16 + col];
        ajv[nt] = a[w * (2 * DIM_OUT) + DIM_OUT + nt * 16 + col];
    }
#pragma unroll
    for (int mt = 0; mt < 4; ++mt) {
#pragma unroll
        for (int r = 0; r < 4; ++r) {
            float pi = 0.f, pj = 0.f;
#pragma unroll
            for (int nt = 0; nt < 4; ++nt) {
                pi = fmaf(acc[mt][nt][r], aiv[nt], pi);
                pj = fmaf(acc[mt][nt][r], ajv[nt], pj);
            }
#pragma unroll
            for (int off = 8; off > 0; off >>= 1) {
                pi += __shfl_down(pi, off, 16);
                pj += __shfl_down(pj, off, 16);
            }
            if (col == 0) {
                const int n = nb + mt * 16 + quad * 4 + r;
                s_i[n * HEADS + w] = pi;
                s_j[n * HEADS + w] = pj;
            }
        }
    }
    __syncthreads();   // xh/xl consumed; smem becomes the transpose buffer

    // stage transposed bf16 tile: lt[node][o*4+head] with padded row stride
    short* lt = (short*)smemv;
#pragma unroll
    for (int mt = 0; mt < 4; ++mt)
#pragma unroll
        for (int nt = 0; nt < 4; ++nt)
#pragma unroll
            for (int r = 0; r < 4; ++r)
                lt[(mt * 16 + quad * 4 + r) * LTROW + (nt * 16 + col) * 4 + w] =
                    (short)f2bf(acc[mt][nt][r]);
    __syncthreads();

    // dense write-out: 4096 uint2 = 32 KB, coalesced 8B stores
    uint2* hg = (uint2*)(h2 + (size_t)nb * (DIM_OUT * HEADS));
#pragma unroll
    for (int r = 0; r < 16; ++r) {
        const int idx = t + 256 * r;       // 0..4095
        const int node = idx >> 6;
        const int wo = idx & 63;
        hg[idx] = *(const uint2*)(lt + node * LTROW + wo * 4);
    }
}

// ---------------- D2: csr blocks [0,128) ∥ MFMA-gemm blocks [128,910) -------------
__global__ __launch_bounds__(256) void csr_gemm_kernel(
    const float* __restrict__ x, const unsigned short* __restrict__ Wph,
    const unsigned short* __restrict__ Wpl, const float* __restrict__ a,
    unsigned short* __restrict__ h2, float* __restrict__ s_i, float* __restrict__ s_j,
    const unsigned int* __restrict__ ebuf2, const unsigned short* __restrict__ cnt,
    unsigned short* __restrict__ sdst)
{
    __shared__ __align__(16) unsigned char smem[SMEM_BYTES];  // 34816 B, dual-use
    const int b = blockIdx.x;
    const int t = threadIdx.x;

    if (b < RANGES) {
        unsigned int* cur = (unsigned int*)smem;       // [RSPAN]
        unsigned int* off_s = cur + RSPAN;             // [CHUNKS+1]
        const int r = b;
        for (int i = t; i < RSPAN; i += 256) cur[i] = 0u;
        if (t < CHUNKS) off_s[t + 1] = (unsigned int)cnt[t * RANGES + r];
        if (t == 0) off_s[0] = 0u;
        __syncthreads();
        // Hillis-Steele inclusive scan over off_s[1..128]
        for (int off = 1; off < CHUNKS; off <<= 1) {
            unsigned int v = 0u;
            if (t < CHUNKS && (t + 1) > off) v = off_s[t + 1 - off];
            __syncthreads();
            if (t < CHUNKS) off_s[t + 1] += v;
            __syncthreads();
        }
        const int total = (int)off_s[CHUNKS];
        // thread-per-edge: independent iterations, deep MLP
        for (int i = t; i < total; i += 256) {
            int lo = 0, hi = CHUNKS;                   // find chunk: off_s[lo] <= i < off_s[lo+1]
            while (hi - lo > 1) {
                const int mid = (lo + hi) >> 1;
                if ((int)off_s[mid] <= i) lo = mid; else hi = mid;
            }
            const int e = i - (int)off_s[lo];
            const unsigned int v = ebuf2[((size_t)lo * RANGES + r) * BCAP + e];
            const unsigned int sl = v >> 16;
            const unsigned int d = v & 0xFFFFu;
            const unsigned int slot = atomicAdd(&cur[sl], 1u);
            if (slot < MAXD) sdst[(size_t)(r * RSPAN + sl) * PAD + 1 + slot] = (unsigned short)d;
        }
        __syncthreads();
        for (int i = t; i < RSPAN; i += 256) {
            const int n = r * RSPAN + i;
            if (n < N_NODES) sdst[(size_t)n * PAD] = (unsigned short)min(cur[i], (unsigned int)MAXD);
        }
        return;
    }

    gemm_role((b - RANGES) * NPB, t, x, Wph, Wpl, a, h2, s_i, s_j, smem);
}

// ---------------- D3: fused softmax + aggregate (at L3-traffic floor ~58 us) ------
__global__ __launch_bounds__(256) void fused_kernel(
    const unsigned short* __restrict__ sdst,
    const float* __restrict__ s_i, const float* __restrict__ s_j,
    const unsigned short* __restrict__ h2, float* __restrict__ out)
{
    __shared__ float4 att_s[4][64];
    __shared__ int    dst_s[4][64];
    const int w = (threadIdx.x >> 6) & 3;
    const int lane = threadIdx.x & 63;
    const int n = blockIdx.x * 4 + w;
    if (n >= N_NODES) return;

    // one coalesced row read: lane0 = degree, lanes 1..d = dst indices
    const int myv = (int)sdst[(size_t)n * PAD + lane];
    const int d = __shfl(myv, 0, 64);

    if (d == 0) { out[n * DIM_OUT + lane] = 0.f; return; }

    att_s[w][lane] = make_float4(0.f, 0.f, 0.f, 0.f);
    dst_s[w][lane] = 0;
    const bool has_edge = (lane >= 1) && (lane <= d);
    if (has_edge) dst_s[w][lane - 1] = myv;

    // issue gather batch-0 NOW (hides under s_j load + softmax below)
    const unsigned short* hbase = h2 + lane * HEADS;
    uint2 hv[8];
#pragma unroll
    for (int q = 0; q < 8; ++q)
        hv[q] = *(const uint2*)(hbase + (size_t)dst_s[w][q] * (DIM_OUT * HEADS));

    // softmax (no max subtraction; raw exp, normalize once at the end)
    const float4 si = *(const float4*)(s_i + n * HEADS);
    float4 ex = {0.f, 0.f, 0.f, 0.f};
    if (has_edge) {
        const float4 sj = *(const float4*)(s_j + myv * HEADS);
        float z0 = si.x + sj.x, z1 = si.y + sj.y, z2 = si.z + sj.z, z3 = si.w + sj.w;
        z0 = z0 >= 0.f ? z0 : NEG_SLOPE * z0;
        z1 = z1 >= 0.f ? z1 : NEG_SLOPE * z1;
        z2 = z2 >= 0.f ? z2 : NEG_SLOPE * z2;
        z3 = z3 >= 0.f ? z3 : NEG_SLOPE * z3;
        ex.x = __expf(z0);
        ex.y = __expf(z1);
        ex.z = __expf(z2);
        ex.w = __expf(z3);
    }
    float4 sm = ex;
#pragma unroll
    for (int off = 32; off > 0; off >>= 1) {
        sm.x += __shfl_xor(sm.x, off, 64);
        sm.y += __shfl_xor(sm.y, off, 64);
        sm.z += __shfl_xor(sm.z, off, 64);
        sm.w += __shfl_xor(sm.w, off, 64);
    }
    if (has_edge) att_s[w][lane - 1] = ex;     // raw ex; normalize once at the end

    float a0 = 0.f, a1 = 0.f, a2 = 0.f, a3 = 0.f;
    const int nb8 = (d + 7) >> 3;
    int bb = 0;
    while (true) {
#pragma unroll
        for (int q = 0; q < 8; ++q) {
            const float4 at = att_s[w][bb * 8 + q];
            const uint2 v = hv[q];
            a0 = fmaf(at.x, __uint_as_float(v.x << 16), a0);
            a1 = fmaf(at.y, __uint_as_float(v.x & 0xFFFF0000u), a1);
            a2 = fmaf(at.z, __uint_as_float(v.y << 16), a2);
            a3 = fmaf(at.w, __uint_as_float(v.y & 0xFFFF0000u), a3);
        }
        if (++bb >= nb8) break;
#pragma unroll
        for (int q = 0; q < 8; ++q)
            hv[q] = *(const uint2*)(hbase + (size_t)dst_s[w][bb * 8 + q] * (DIM_OUT * HEADS));
    }

    out[n * DIM_OUT + lane] = 0.25f * (a0 / sm.x + a1 / sm.y + a2 / sm.z + a3 / sm.w);
}

extern "C" void kernel_launch(void* const* d_in, const int* in_sizes, int n_in,
                              void* d_out, int out_size, void* d_ws, size_t ws_size,
                              hipStream_t stream) {
    const float* x  = (const float*)d_in[0];
    const int*   ei = (const int*)d_in[1];
    const float* W  = (const float*)d_in[2];
    const float* a  = (const float*)d_in[3];
    float* out = (float*)d_out;

    char* ws = (char*)d_ws;
    size_t off = 0;
    auto alloc = [&](size_t bytes) { void* p = ws + off; off = (off + bytes + 511) & ~size_t(511); return p; };
    unsigned short* h2  = (unsigned short*)alloc(sizeof(unsigned short) * N_PAD * DIM_OUT * HEADS); // 25.6 MB
    float* s_i    = (float*)alloc(sizeof(float) * N_PAD * HEADS);
    float* s_j    = (float*)alloc(sizeof(float) * N_PAD * HEADS);
    unsigned short* sdst = (unsigned short*)alloc(sizeof(unsigned short) * N_NODES * PAD); // 6.4 MB
    unsigned int* ebuf2  = (unsigned int*)alloc(sizeof(unsigned int) * CHUNKS * RANGES * BCAP); // 8.4 MB
    unsigned short* cnt  = (unsigned short*)alloc(sizeof(unsigned short) * CHUNKS * RANGES);    // 32 KB
    unsigned short* Wph  = (unsigned short*)alloc(sizeof(unsigned short) * HEADS * DIM_IN * DIM_OUT); // 64 KB
    unsigned short* Wpl  = (unsigned short*)alloc(sizeof(unsigned short) * HEADS * DIM_IN * DIM_OUT); // 64 KB

    // D1: pack W (8 blocks) + single-pass bucket scatter (128 blocks)
    bucket_kernel<<<8 + CHUNKS, 512, 0, stream>>>(W, Wph, Wpl, ei, ebuf2, cnt);

    // D2: flattened single-writer CSR build (128 blocks) + MFMA gemm (782 blocks)
    csr_gemm_kernel<<<RANGES + GEMM_BLOCKS, 256, 0, stream>>>(
        x, Wph, Wpl, a, h2, s_i, s_j, ebuf2, cnt, sdst);

    // D3: fused softmax + aggregate: one wave per node
    const int fb = (N_NODES + 3) / 4;
    fused_kernel<<<fb, 256, 0, stream>>>(sdst, s_i, s_j, h2, out);
}

// Round 12
// 164.208 us; speedup vs baseline: 1.0848x; 1.0848x over previous
//
#include <hip/hip_runtime.h>
#include <hip/hip_bf16.h>

#define N_NODES 50000
#define N_EDGES 800000
#define DIM_IN  128
#define DIM_OUT 64
#define HEADS   4
#define NEG_SLOPE 0.2f
#define NPB 32                                    // nodes per gemm block (R7 best)
#define GEMM_BLOCKS ((N_NODES + NPB - 1) / NPB)   // 1563
#define N_PAD (GEMM_BLOCKS * NPB)                 // 50016
#define PAD 64                                    // sdst row: [0]=deg, [1..63]=dsts
#define MAXD 63                                   // max stored dsts per node
#define CHUNKS 128                                // edge chunks
#define EPC (N_EDGES / CHUNKS)                    // 6250 edges per chunk
#define RANGES 128                                // src ranges (single-writer CSR build)
#define RSPAN 391                                 // 128*391 = 50048 >= N_NODES
#define OPITCH 132                                // offT row pitch (129 used, padded)
#define XROW 136                                  // LDS row stride (shorts) for x hi/lo
#define LTROW 260                                 // LDS row stride (shorts) for transpose buffer
#define SMEM_BYTES (2 * NPB * XROW * 2)           // 17408

typedef __attribute__((ext_vector_type(8))) short short8;
typedef __attribute__((ext_vector_type(4))) short short4v;
typedef __attribute__((ext_vector_type(4))) float f32x4;

// bf16 helpers (RNE pack, exact shift unpack)
__device__ __forceinline__ unsigned int f2bf(float f) {
    unsigned int u = __float_as_uint(f);
    return (u + 0x7FFFu + ((u >> 16) & 1u)) >> 16;
}
__device__ __forceinline__ float bf2f(unsigned int b) {
    return __uint_as_float(b << 16);
}

// ---- pack W into MFMA B-frag hi/lo; i = fragment-lane 0..4095
__device__ __forceinline__ void packW_role(
    int i, const float* __restrict__ W,
    unsigned short* __restrict__ Wph, unsigned short* __restrict__ Wpl)
{
    const int lane = i & 63, nt = (i >> 6) & 3, kc = (i >> 8) & 3, h = (i >> 10) & 3;
    const int col = lane & 15, quad = lane >> 4;
    unsigned short hv[8], lv[8];
#pragma unroll
    for (int j = 0; j < 8; ++j) {
        const int k = kc * 32 + quad * 8 + j;
        const int n = nt * 16 + col;
        const float f = W[h * (DIM_IN * DIM_OUT) + k * DIM_OUT + n];
        const unsigned int hb = f2bf(f);
        hv[j] = (unsigned short)hb;
        lv[j] = (unsigned short)f2bf(f - bf2f(hb));
    }
    *(short8*)(Wph + (size_t)i * 8) = *(short8*)hv;
    *(short8*)(Wpl + (size_t)i * 8) = *(short8*)lv;
}

// ---------------- D1: pack W (blocks 0-7) + per-chunk local range-sort (8..135) ---
// R7-proven: LDS histogram -> LDS exclusive scan -> chunk-local DENSELY-PACKED
// sorted ebuf + absolute offsets offT[c][r]. No cross-block deps, no global scan.
__global__ __launch_bounds__(512) void sort_kernel(
    const float* __restrict__ W, unsigned short* __restrict__ Wph,
    unsigned short* __restrict__ Wpl, const int* __restrict__ ei,
    unsigned int* __restrict__ offT, unsigned int* __restrict__ ebuf)
{
    const int b = blockIdx.x;
    const int t = threadIdx.x;
    if (b < 8) { packW_role(b * 512 + t, W, Wph, Wpl); return; }

    __shared__ unsigned int hist[RANGES];
    __shared__ unsigned int scn[RANGES + 1];
    __shared__ unsigned int cur[RANGES];
    const int c = b - 8;
    if (t < RANGES) hist[t] = 0u;
    __syncthreads();
    const int* srcp = ei + c * EPC;
    const int* dstp = ei + N_EDGES + c * EPC;
    for (int e = t; e < EPC; e += 512) atomicAdd(&hist[srcp[e] / RSPAN], 1u);
    __syncthreads();
    // Hillis-Steele scan (threads 0..127), exclusive via scn[t+1]=hist[t]
    if (t < RANGES) scn[t + 1] = hist[t];
    if (t == 0) scn[0] = 0u;
    __syncthreads();
    for (int off = 1; off < RANGES; off <<= 1) {
        unsigned int v = 0u;
        if (t < RANGES && (t + 1) > off) v = scn[t + 1 - off];
        __syncthreads();
        if (t < RANGES) scn[t + 1] += v;
        __syncthreads();
    }
    if (t < RANGES) {
        cur[t] = scn[t];
        offT[c * OPITCH + t] = (unsigned int)(c * EPC) + scn[t];
    }
    if (t == 0) offT[c * OPITCH + RANGES] = (unsigned int)((c + 1) * EPC);
    __syncthreads();
    unsigned int* eb = ebuf + (size_t)c * EPC;
    for (int e = t; e < EPC; e += 512) {
        const int s = srcp[e];
        const int d = dstp[e];
        const int r = s / RSPAN;
        const unsigned int pos = atomicAdd(&cur[r], 1u);
        eb[pos] = ((unsigned int)(s - r * RSPAN) << 16) | (unsigned int)d;
    }
}

// ---- MFMA gemm tile for nodes [nb, nb+32) (256 threads, smem = 17408 B)
__device__ __forceinline__ void gemm_role(
    int nb, int t, const float* __restrict__ x,
    const unsigned short* __restrict__ Wph, const unsigned short* __restrict__ Wpl,
    const float* __restrict__ a, unsigned short* __restrict__ h2,
    float* __restrict__ s_i, float* __restrict__ s_j, void* smemv)
{
    short* xh = (short*)smemv;            // [NPB][XROW]
    short* xl = xh + NPB * XROW;

    // stage x tile as hi/lo bf16 (hi = truncation, lo = RNE residual: hi+lo ~ fp32)
    {
        const float4* xg = (const float4*)x;
        const int base = nb * (DIM_IN / 4);
        const int limit = N_NODES * (DIM_IN / 4);
#pragma unroll
        for (int r = 0; r < 4; ++r) {
            const int idx = t + 256 * r;              // 0..1023
            const int gi = base + idx;
            float4 v = {0.f, 0.f, 0.f, 0.f};
            if (gi < limit) v = xg[gi];
            const int node = idx >> 5;
            const int dg = (idx & 31) * 4;
            unsigned short hs[4], ls[4];
            const float fv[4] = {v.x, v.y, v.z, v.w};
#pragma unroll
            for (int c = 0; c < 4; ++c) {
                const unsigned int hb = __float_as_uint(fv[c]) >> 16;  // trunc hi (1 op)
                hs[c] = (unsigned short)hb;
                ls[c] = (unsigned short)f2bf(fv[c] - bf2f(hb));        // exact residual
            }
            *(short4v*)(xh + node * XROW + dg) = *(short4v*)hs;
            *(short4v*)(xl + node * XROW + dg) = *(short4v*)ls;
        }
    }
    __syncthreads();

    const int w = t >> 6;        // wave id == head
    const int lane = t & 63;
    const int col = lane & 15, quad = lane >> 4;

    f32x4 acc[2][4];
#pragma unroll
    for (int mt = 0; mt < 2; ++mt)
#pragma unroll
        for (int nt = 0; nt < 4; ++nt) acc[mt][nt] = (f32x4){0.f, 0.f, 0.f, 0.f};

    const short8* Bh = (const short8*)Wph;
    const short8* Bl = (const short8*)Wpl;
#pragma unroll
    for (int kc = 0; kc < 4; ++kc) {
        const short8 ah0 = *(const short8*)(xh + (0 * 16 + col) * XROW + kc * 32 + quad * 8);
        const short8 al0 = *(const short8*)(xl + (0 * 16 + col) * XROW + kc * 32 + quad * 8);
        const short8 ah1 = *(const short8*)(xh + (1 * 16 + col) * XROW + kc * 32 + quad * 8);
        const short8 al1 = *(const short8*)(xl + (1 * 16 + col) * XROW + kc * 32 + quad * 8);
#pragma unroll
        for (int nt = 0; nt < 4; ++nt) {
            const int fi = ((w * 4 + kc) * 4 + nt) * 64 + lane;
            const short8 bh = Bh[fi];
            const short8 bl = Bl[fi];
            acc[0][nt] = __builtin_amdgcn_mfma_f32_16x16x32_bf16(ah0, bh, acc[0][nt], 0, 0, 0);
            acc[0][nt] = __builtin_amdgcn_mfma_f32_16x16x32_bf16(al0, bh, acc[0][nt], 0, 0, 0);
            acc[0][nt] = __builtin_amdgcn_mfma_f32_16x16x32_bf16(ah0, bl, acc[0][nt], 0, 0, 0);
            acc[1][nt] = __builtin_amdgcn_mfma_f32_16x16x32_bf16(ah1, bh, acc[1][nt], 0, 0, 0);
            acc[1][nt] = __builtin_amdgcn_mfma_f32_16x16x32_bf16(al1, bh, acc[1][nt], 0, 0, 0);
            acc[1][nt] = __builtin_amdgcn_mfma_f32_16x16x32_bf16(ah1, bl, acc[1][nt], 0, 0, 0);
        }
    }

    // scores: lane holds h[node=mt*16+quad*4+r][head=w][o=nt*16+col]
    float aiv[4], ajv[4];
#pragma unroll
    for (int nt = 0; nt < 4; ++nt) {
        aiv[nt] = a[w * (2 * DIM_OUT) + nt * 16 + col];
        ajv[nt] = a[w * (2 * DIM_OUT) + DIM_OUT + nt * 16 + col];
    }
#pragma unroll
    for (int mt = 0; mt < 2; ++mt) {
#pragma unroll
        for (int r = 0; r < 4; ++r) {
            float pi = 0.f, pj = 0.f;
#pragma unroll
            for (int nt = 0; nt < 4; ++nt) {
                pi = fmaf(acc[mt][nt][r], aiv[nt], pi);
                pj = fmaf(acc[mt][nt][r], ajv[nt], pj);
            }
#pragma unroll
            for (int off = 8; off > 0; off >>= 1) {
                pi += __shfl_down(pi, off, 16);
                pj += __shfl_down(pj, off, 16);
            }
            if (col == 0) {
                const int n = nb + mt * 16 + quad * 4 + r;
                s_i[n * HEADS + w] = pi;
                s_j[n * HEADS + w] = pj;
            }
        }
    }
    __syncthreads();   // xh/xl consumed; smem becomes the transpose buffer

    // stage transposed bf16 tile: lt[node][o*4+head] with padded row stride
    short* lt = (short*)smemv;
#pragma unroll
    for (int mt = 0; mt < 2; ++mt)
#pragma unroll
        for (int nt = 0; nt < 4; ++nt)
#pragma unroll
            for (int r = 0; r < 4; ++r)
                lt[(mt * 16 + quad * 4 + r) * LTROW + (nt * 16 + col) * 4 + w] =
                    (short)f2bf(acc[mt][nt][r]);
    __syncthreads();

    // dense write-out: 2048 uint2 = 16 KB, coalesced 8B stores
    uint2* hg = (uint2*)(h2 + (size_t)nb * (DIM_OUT * HEADS));
#pragma unroll
    for (int r = 0; r < 8; ++r) {
        const int idx = t + 256 * r;       // 0..2047
        const int node = idx >> 6;
        const int wo = idx & 63;
        hg[idx] = *(const uint2*)(lt + node * LTROW + wo * 4);
    }
}

// ---------------- D2: csr blocks [0,128) ∥ MFMA-gemm blocks [128,1691) ------------
// csr block r (R7-proven serial walk): 4 waves x 32 chunk-runs via offT; single
// writer of range r's sdst rows. Header layout: [0]=deg, [1..deg]=dsts.
__global__ __launch_bounds__(256) void csr_gemm_kernel(
    const float* __restrict__ x, const unsigned short* __restrict__ Wph,
    const unsigned short* __restrict__ Wpl, const float* __restrict__ a,
    unsigned short* __restrict__ h2, float* __restrict__ s_i, float* __restrict__ s_j,
    const unsigned int* __restrict__ offT, const unsigned int* __restrict__ ebuf,
    unsigned short* __restrict__ sdst)
{
    __shared__ __align__(16) unsigned char smem[SMEM_BYTES];  // 17408 B, dual-use
    const int b = blockIdx.x;
    const int t = threadIdx.x;

    if (b < RANGES) {
        unsigned int* cur  = (unsigned int*)smem;      // [RSPAN]
        unsigned int* offA = cur + RSPAN;              // [CHUNKS]
        unsigned int* offB = offA + CHUNKS;            // [CHUNKS]
        const int r = b;
        for (int i = t; i < RSPAN; i += 256) cur[i] = 0u;
        if (t < CHUNKS) {
            offA[t] = offT[t * OPITCH + r];
            offB[t] = offT[t * OPITCH + r + 1];
        }
        __syncthreads();
        const int w = t >> 6, lane = t & 63;
        for (int c = w; c < CHUNKS; c += 4) {
            const unsigned int j0 = offA[c], j1 = offB[c];
            for (unsigned int e = j0 + lane; e < j1; e += 64) {
                const unsigned int v = ebuf[e];
                const unsigned int sl = v >> 16;
                const unsigned int d = v & 0xFFFFu;
                const unsigned int slot = atomicAdd(&cur[sl], 1u);
                if (slot < MAXD) sdst[(size_t)(r * RSPAN + sl) * PAD + 1 + slot] = (unsigned short)d;
            }
        }
        __syncthreads();
        for (int i = t; i < RSPAN; i += 256) {
            const int n = r * RSPAN + i;
            if (n < N_NODES) sdst[(size_t)n * PAD] = (unsigned short)min(cur[i], (unsigned int)MAXD);
        }
        return;
    }

    gemm_role((b - RANGES) * NPB, t, x, Wph, Wpl, a, h2, s_i, s_j, smem);
}

// ---------------- D3: fused softmax + aggregate (at L3-traffic floor ~58 us) ------
// Header row read (deg inline) + batch-0 prefetch + max-elided softmax (shift-
// invariant; |z| << 80 so exp cannot overflow) + zero-padded att (no tails).
__global__ __launch_bounds__(256) void fused_kernel(
    const unsigned short* __restrict__ sdst,
    const float* __restrict__ s_i, const float* __restrict__ s_j,
    const unsigned short* __restrict__ h2, float* __restrict__ out)
{
    __shared__ float4 att_s[4][64];
    __shared__ int    dst_s[4][64];
    const int w = (threadIdx.x >> 6) & 3;
    const int lane = threadIdx.x & 63;
    const int n = blockIdx.x * 4 + w;
    if (n >= N_NODES) return;

    // one coalesced row read: lane0 = degree, lanes 1..d = dst indices
    const int myv = (int)sdst[(size_t)n * PAD + lane];
    const int d = __shfl(myv, 0, 64);

    if (d == 0) { out[n * DIM_OUT + lane] = 0.f; return; }

    att_s[w][lane] = make_float4(0.f, 0.f, 0.f, 0.f);
    dst_s[w][lane] = 0;
    const bool has_edge = (lane >= 1) && (lane <= d);
    if (has_edge) dst_s[w][lane - 1] = myv;

    // issue gather batch-0 NOW (hides under s_j load + softmax below)
    const unsigned short* hbase = h2 + lane * HEADS;
    uint2 hv[8];
#pragma unroll
    for (int q = 0; q < 8; ++q)
        hv[q] = *(const uint2*)(hbase + (size_t)dst_s[w][q] * (DIM_OUT * HEADS));

    // softmax (no max subtraction; raw exp, normalize once at the end)
    const float4 si = *(const float4*)(s_i + n * HEADS);
    float4 ex = {0.f, 0.f, 0.f, 0.f};
    if (has_edge) {
        const float4 sj = *(const float4*)(s_j + myv * HEADS);
        float z0 = si.x + sj.x, z1 = si.y + sj.y, z2 = si.z + sj.z, z3 = si.w + sj.w;
        z0 = z0 >= 0.f ? z0 : NEG_SLOPE * z0;
        z1 = z1 >= 0.f ? z1 : NEG_SLOPE * z1;
        z2 = z2 >= 0.f ? z2 : NEG_SLOPE * z2;
        z3 = z3 >= 0.f ? z3 : NEG_SLOPE * z3;
        ex.x = __expf(z0);
        ex.y = __expf(z1);
        ex.z = __expf(z2);
        ex.w = __expf(z3);
    }
    float4 sm = ex;
#pragma unroll
    for (int off = 32; off > 0; off >>= 1) {
        sm.x += __shfl_xor(sm.x, off, 64);
        sm.y += __shfl_xor(sm.y, off, 64);
        sm.z += __shfl_xor(sm.z, off, 64);
        sm.w += __shfl_xor(sm.w, off, 64);
    }
    if (has_edge) att_s[w][lane - 1] = ex;     // raw ex; normalize once at the end

    float a0 = 0.f, a1 = 0.f, a2 = 0.f, a3 = 0.f;
    const int nb8 = (d + 7) >> 3;
    int bb = 0;
    while (true) {
#pragma unroll
        for (int q = 0; q < 8; ++q) {
            const float4 at = att_s[w][bb * 8 + q];
            const uint2 v = hv[q];
            a0 = fmaf(at.x, __uint_as_float(v.x << 16), a0);
            a1 = fmaf(at.y, __uint_as_float(v.x & 0xFFFF0000u), a1);
            a2 = fmaf(at.z, __uint_as_float(v.y << 16), a2);
            a3 = fmaf(at.w, __uint_as_float(v.y & 0xFFFF0000u), a3);
        }
        if (++bb >= nb8) break;
#pragma unroll
        for (int q = 0; q < 8; ++q)
            hv[q] = *(const uint2*)(hbase + (size_t)dst_s[w][bb * 8 + q] * (DIM_OUT * HEADS));
    }

    out[n * DIM_OUT + lane] = 0.25f * (a0 / sm.x + a1 / sm.y + a2 / sm.z + a3 / sm.w);
}

extern "C" void kernel_launch(void* const* d_in, const int* in_sizes, int n_in,
                              void* d_out, int out_size, void* d_ws, size_t ws_size,
                              hipStream_t stream) {
    const float* x  = (const float*)d_in[0];
    const int*   ei = (const int*)d_in[1];
    const float* W  = (const float*)d_in[2];
    const float* a  = (const float*)d_in[3];
    float* out = (float*)d_out;

    char* ws = (char*)d_ws;
    size_t off = 0;
    auto alloc = [&](size_t bytes) { void* p = ws + off; off = (off + bytes + 511) & ~size_t(511); return p; };
    unsigned short* h2  = (unsigned short*)alloc(sizeof(unsigned short) * N_PAD * DIM_OUT * HEADS); // 25.6 MB
    float* s_i    = (float*)alloc(sizeof(float) * N_PAD * HEADS);
    float* s_j    = (float*)alloc(sizeof(float) * N_PAD * HEADS);
    unsigned short* sdst = (unsigned short*)alloc(sizeof(unsigned short) * N_NODES * PAD); // 6.4 MB
    unsigned int* offT   = (unsigned int*)alloc(sizeof(unsigned int) * CHUNKS * OPITCH);   // 67.6 KB
    unsigned int* ebuf   = (unsigned int*)alloc(sizeof(unsigned int) * N_EDGES);// 3.2 MB
    unsigned short* Wph  = (unsigned short*)alloc(sizeof(unsigned short) * HEADS * DIM_IN * DIM_OUT); // 64 KB
    unsigned short* Wpl  = (unsigned short*)alloc(sizeof(unsigned short) * HEADS * DIM_IN * DIM_OUT); // 64 KB

    // D1: pack W (8 blocks) + per-chunk local range-sort (128 blocks)
    sort_kernel<<<8 + CHUNKS, 512, 0, stream>>>(W, Wph, Wpl, ei, offT, ebuf);

    // D2: single-writer CSR build (128 blocks) + MFMA gemm (1563 blocks)
    csr_gemm_kernel<<<RANGES + GEMM_BLOCKS, 256, 0, stream>>>(
        x, Wph, Wpl, a, h2, s_i, s_j, offT, ebuf, sdst);

    // D3: fused softmax + aggregate: one wave per node
    const int fb = (N_NODES + 3) / 4;
    fused_kernel<<<fb, 256, 0, stream>>>(sdst, s_i, s_j, h2, out);
}